// Round 4
// baseline (65.096 us; speedup 1.0000x reference)
//
#include <hip/hip_runtime.h>

// FocusingLoss forward, fused. B*WL=128 images of 512x512 fp32.
// stream_kernel: one pass over pred+tgt (268 MB), register double-buffered
//   (batch=4 float4 per array in flight while computing previous batch).
//   1024 blocks (8/image) -> fully resident, no tail. Per block: 8 partial
//   moments {ts,ty,tx,mse,m0,my,mx,m2} -> unique ws slot (no atomics).
//   spread = m2 - 2cy*my - 2cx*mx + (cy^2+cx^2)*m0 (centroid-independent).
// focus_kernel: per-image (128 blocks x 256 thr): reduce 8 partials,
//   centroid, window-sum pred over <=43x43 disc (L3-hit), emit per-image
//   loss term + mse as doubles.
// final_kernel: 128-thread double sum.

#define HH 512
#define WW 512
#define IMG_PIX (HH * WW)                           // 262144
#define VEC_PER_IMG (IMG_PIX / 4)                   // 65536 float4
#define BLOCKS_PER_IMG 8
#define VEC_PER_BLK (VEC_PER_IMG / BLOCKS_PER_IMG)  // 8192
#define THREADS 256
#define ITERS (VEC_PER_BLK / THREADS)               // 32
#define BATCH 4
#define NBATCH (ITERS / BATCH)                      // 8
#define EPSF 1e-8f
#define R2 400.0f

typedef float f4 __attribute__((ext_vector_type(4)));

__device__ __forceinline__ float wave_reduce_sum(float v) {
    v += __shfl_down(v, 32);
    v += __shfl_down(v, 16);
    v += __shfl_down(v, 8);
    v += __shfl_down(v, 4);
    v += __shfl_down(v, 2);
    v += __shfl_down(v, 1);
    return v;
}

__device__ __forceinline__ double wave_reduce_sum_d(double v) {
    v += __shfl_down(v, 32);
    v += __shfl_down(v, 16);
    v += __shfl_down(v, 8);
    v += __shfl_down(v, 4);
    v += __shfl_down(v, 2);
    v += __shfl_down(v, 1);
    return v;
}

// part[block*8 + k], k: 0:ts 1:ty 2:tx 3:mse 4:m0 5:my 6:mx 7:m2
__global__ void __launch_bounds__(THREADS) stream_kernel(
        const f4* __restrict__ pred, const f4* __restrict__ tgt,
        float* __restrict__ part) {
    const int img = blockIdx.x / BLOCKS_PER_IMG;
    const int sub = blockIdx.x % BLOCKS_PER_IMG;
    const int base = img * VEC_PER_IMG + sub * VEC_PER_BLK + (int)threadIdx.x;

    f4 tb[2][BATCH], pb[2][BATCH];
#pragma unroll
    for (int u = 0; u < BATCH; ++u) {
        tb[0][u] = __builtin_nontemporal_load(&tgt[base + u * THREADS]);
        pb[0][u] = pred[base + u * THREADS];
    }

    float ts = 0.f, ty = 0.f, tx = 0.f, mse = 0.f;
    float m0 = 0.f, my = 0.f, mx = 0.f, m2 = 0.f;

#pragma unroll
    for (int b = 0; b < NBATCH; ++b) {
        const int cur = b & 1, nxt = cur ^ 1;
        if (b + 1 < NBATCH) {
#pragma unroll
            for (int u = 0; u < BATCH; ++u) {
                const int v = base + ((b + 1) * BATCH + u) * THREADS;
                tb[nxt][u] = __builtin_nontemporal_load(&tgt[v]);
                pb[nxt][u] = pred[v];
            }
        }
#pragma unroll
        for (int u = 0; u < BATCH; ++u) {
            const int iv = sub * VEC_PER_BLK + (b * BATCH + u) * THREADS
                         + (int)threadIdx.x;          // within-image vec idx
            const float y  = (float)(iv >> 7);        // row (const per float4)
            const float x0 = (float)((iv & 127) << 2);
            const f4 tv = tb[cur][u];
            const f4 pv = pb[cur][u];

            const float tsum = tv[0] + tv[1] + tv[2] + tv[3];
            const float tw1  = tv[1] + 2.f * tv[2] + 3.f * tv[3];
            ts += tsum;
            ty += y * tsum;
            tx += x0 * tsum + tw1;

            const float d0 = pv[0] - tv[0], d1 = pv[1] - tv[1],
                        d2 = pv[2] - tv[2], d3 = pv[3] - tv[3];
            mse += d0 * d0 + d1 * d1 + d2 * d2 + d3 * d3;

            const float psum = pv[0] + pv[1] + pv[2] + pv[3];
            const float pw1  = pv[1] + 2.f * pv[2] + 3.f * pv[3];
            const float pw2  = pv[1] + 4.f * pv[2] + 9.f * pv[3];
            m0 += psum;
            my += y * psum;
            mx += x0 * psum + pw1;
            const float r2c = y * y + x0 * x0;
            m2 += r2c * psum + 2.f * x0 * pw1 + pw2;
        }
    }

    float vals[8] = {ts, ty, tx, mse, m0, my, mx, m2};
    __shared__ float red[4][8];
    const int wid = threadIdx.x >> 6, lane = threadIdx.x & 63;
#pragma unroll
    for (int k = 0; k < 8; ++k) vals[k] = wave_reduce_sum(vals[k]);
    if (lane == 0)
#pragma unroll
        for (int k = 0; k < 8; ++k) red[wid][k] = vals[k];
    __syncthreads();
    if (threadIdx.x < 8) {
        const int k = threadIdx.x;
        part[blockIdx.x * 8 + k] = red[0][k] + red[1][k] + red[2][k] + red[3][k];
    }
}

// one 256-thread block per image: reduce partials, centroid, disc window sum,
// emit per-image {loss_term, mse} as doubles.
__global__ void __launch_bounds__(THREADS) focus_kernel(
        const float* __restrict__ pred, const float* __restrict__ part,
        double* __restrict__ vout, double* __restrict__ mout) {
    const int img = blockIdx.x;
    const int tid = threadIdx.x;
    __shared__ float mom[8];
    {
        float v[8] = {0.f, 0.f, 0.f, 0.f, 0.f, 0.f, 0.f, 0.f};
        if (tid < BLOCKS_PER_IMG) {
            const float* p = part + (img * BLOCKS_PER_IMG + tid) * 8;
#pragma unroll
            for (int k = 0; k < 8; ++k) v[k] = p[k];
        }
        if (tid < 64) {
#pragma unroll
            for (int k = 0; k < 8; ++k) v[k] = wave_reduce_sum(v[k]);
            if (tid == 0)
#pragma unroll
                for (int k = 0; k < 8; ++k) mom[k] = v[k];
        }
    }
    __syncthreads();

    const float ts = mom[0];
    float fe = 0.f;
    float cy = 0.f, cx = 0.f;
    if (ts >= EPSF) {
        cy = mom[1] / ts;
        cx = mom[2] / ts;
        const int ylo = max(0, (int)ceilf(cy - 20.f) - 1);
        const int yhi = min(HH - 1, (int)floorf(cy + 20.f) + 1);
        const int xlo = max(0, (int)ceilf(cx - 20.f) - 1);
        const int xhi = min(WW - 1, (int)floorf(cx + 20.f) + 1);
        const float* p = pred + (size_t)img * IMG_PIX;
        const int lane = tid & 63, w = tid >> 6;   // lane->column, wave->row stripe
        const int xx = xlo + lane;
        if (xx <= xhi) {
            const float dx = (float)xx - cx;
            const float dx2 = dx * dx;
            for (int y = ylo + w; y <= yhi; y += 4) {
                const float dy = (float)y - cy;
                if (dy * dy + dx2 <= R2) fe += p[(y << 9) + xx];
            }
        }
    }
    __shared__ float redf[4];
    fe = wave_reduce_sum(fe);
    if ((tid & 63) == 0) redf[tid >> 6] = fe;
    __syncthreads();
    if (tid == 0) {
        const float fet = redf[0] + redf[1] + redf[2] + redf[3];
        const float m0 = mom[4];
        double v = 0.0;
        if (ts >= EPSF && m0 > EPSF) {
            const double dcy = (double)mom[1] / (double)ts;
            const double dcx = (double)mom[2] / (double)ts;
            const double spread = (double)mom[7] - 2.0 * dcy * (double)mom[5]
                                - 2.0 * dcx * (double)mom[6]
                                + (dcy * dcy + dcx * dcx) * (double)m0;
            const double r = 1.0 - (double)fet / (double)m0;
            v = 10.0 * r * r + spread / (double)m0;
        }
        vout[img] = v;
        mout[img] = (double)mom[3];
    }
}

__global__ void __launch_bounds__(128) final_kernel(
        const double* __restrict__ vout, const double* __restrict__ mout,
        float* __restrict__ out, int nimg, double inv_n) {
    const int i = threadIdx.x;
    double v = 0.0, m = 0.0;
    if (i < nimg) { v = vout[i]; m = mout[i]; }
    __shared__ double redv[2], redm[2];
    v = wave_reduce_sum_d(v);
    m = wave_reduce_sum_d(m);
    if ((i & 63) == 0) { redv[i >> 6] = v; redm[i >> 6] = m; }
    __syncthreads();
    if (i == 0)
        out[0] = (float)((redm[0] + redm[1]) * inv_n + redv[0] + redv[1]);
}

extern "C" void kernel_launch(void* const* d_in, const int* in_sizes, int n_in,
                              void* d_out, int out_size, void* d_ws, size_t ws_size,
                              hipStream_t stream) {
    const float* pred = (const float*)d_in[0];
    const float* tgt  = (const float*)d_in[1];
    float* out = (float*)d_out;

    const int n = in_sizes[0];                 // 33554432
    const int nimg = n / IMG_PIX;              // 128
    const int nblk = nimg * BLOCKS_PER_IMG;    // 1024

    float* part = (float*)d_ws;                          // nblk*8 floats = 32 KB
    double* vout = (double*)((char*)d_ws + 32768);       // nimg doubles
    double* mout = vout + nimg;                          // nimg doubles
    // every slot is rewritten each call -> deterministic, no zeroing needed

    stream_kernel<<<nblk, THREADS, 0, stream>>>(
        (const f4*)pred, (const f4*)tgt, part);
    focus_kernel<<<nimg, THREADS, 0, stream>>>(pred, part, vout, mout);
    final_kernel<<<1, 128, 0, stream>>>(vout, mout, out, nimg,
                                        1.0 / (double)n);
}